// Round 13
// baseline (142.384 us; speedup 1.0000x reference)
//
#include <hip/hip_runtime.h>
#include <hip/hip_bf16.h>
#include <math.h>

#define BS   32
#define IC   64
#define OC   64
#define HH   128
#define WW   128
#define BANK 256
#define ADDR 64
#define WELEM (OC*IC*9)
#define PLANE (HH*WW)

typedef short short8 __attribute__((ext_vector_type(8)));
typedef int   i32x4  __attribute__((ext_vector_type(4)));
typedef float f32x16 __attribute__((ext_vector_type(16)));

__device__ __forceinline__ short f2bf(float f) {
    unsigned u = __builtin_bit_cast(unsigned, f);
    unsigned r = (u + 0x7FFFu + ((u >> 16) & 1u)) >> 16;
    return (short)r;
}

// pack two f32 -> one dword of 2 bf16 (RTE), single HW instruction
__device__ __forceinline__ int cvt_pk_bf2(float lo, float hi) {
    int r;
    asm("v_cvt_pk_bf16_f32 %0, %1, %2" : "=v"(r) : "v"(lo), "v"(hi));
    return r;
}

// ---------------- kernel 1: sel_w = softmax(w_addr @ aspace^T) --------------
__global__ __launch_bounds__(BANK) void k_selw(const float* __restrict__ w_addr,
                                               const float* __restrict__ aspace,
                                               float* __restrict__ sel_w) {
    int b = blockIdx.x;
    int n = threadIdx.x;
    const float* wa = w_addr + b * ADDR;
    const float* as = aspace + n * ADDR;
    float dot = 0.f;
#pragma unroll
    for (int k = 0; k < ADDR; ++k) dot = fmaf(wa[k], as[k], dot);

    __shared__ float red[BANK];
    red[n] = dot; __syncthreads();
    for (int s = BANK / 2; s > 0; s >>= 1) {
        if (n < s) red[n] = fmaxf(red[n], red[n + s]);
        __syncthreads();
    }
    float m = red[0]; __syncthreads();
    float e = expf(dot - m);
    red[n] = e; __syncthreads();
    for (int s = BANK / 2; s > 0; s >>= 1) {
        if (n < s) red[n] += red[n + s];
        __syncthreads();
    }
    sel_w[b * BANK + n] = e / red[0];
}

// ---------------- kernel 2: bias[b][o] -------------------------------------
// 256 blocks = (b, oc-group of 8); thread = (o-local 8, n-slice 32 of 8 n).
// Dots stay in registers; two LDS reduce stages.
__global__ __launch_bounds__(256) void k_bias(const float* __restrict__ b_addr,
                                              const float* __restrict__ aspace,
                                              const float* __restrict__ b_bank,
                                              float* __restrict__ bias) {
    __shared__ float s_m[256], s_s[256], s_w[256];
    int blk = blockIdx.x;            // b*8 + og
    int b   = blk >> 3;
    int og  = blk & 7;
    int tid = threadIdx.x;
    int ol  = tid >> 5;              // 0..7
    int o   = og * 8 + ol;
    int q   = tid & 31;              // n-slice: n = q*8 .. q*8+7

    const float* ba = b_addr + ((size_t)b * OC + o) * ADDR;
    float bav[64];
#pragma unroll
    for (int i = 0; i < 16; ++i)
        *(float4*)&bav[i * 4] = *(const float4*)&ba[i * 4];

    float d[8];
#pragma unroll
    for (int n = 0; n < 8; ++n) {
        const float* ar = aspace + (size_t)(q * 8 + n) * ADDR;
        float s = 0.f;
#pragma unroll
        for (int k = 0; k < 64; ++k) s = fmaf(bav[k], ar[k], s);
        d[n] = s;
    }
    float mx = d[0];
#pragma unroll
    for (int n = 1; n < 8; ++n) mx = fmaxf(mx, d[n]);
    s_m[ol * 32 + q] = mx;
    __syncthreads();
    float M = -1e30f;
    for (int j = 0; j < 32; ++j) M = fmaxf(M, s_m[ol * 32 + j]);

    float s = 0.f, ws = 0.f;
#pragma unroll
    for (int n = 0; n < 8; ++n) {
        float e = expf(d[n] - M);
        s += e;
        ws += e * b_bank[q * 8 + n];
    }
    s_s[ol * 32 + q] = s;
    s_w[ol * 32 + q] = ws;
    __syncthreads();
    if (q == 0) {
        float S = 0.f, W = 0.f;
        for (int j = 0; j < 32; ++j) { S += s_s[ol * 32 + j]; W += s_w[ol * 32 + j]; }
        bias[b * OC + o] = W / S;
    }
}

// ---------------- kernel 3: weight mix -> bf16 (R5-proven split-K) ----------
// wmb[b][tap(9)][icg(8)][oc(64)][ic8(8)]  (bf16)
__global__ __launch_bounds__(256) void k_wmix(const float* __restrict__ sel_w,
                                              const float* __restrict__ w_bank,
                                              __hip_bfloat16* __restrict__ wmb) {
    __shared__ float s_red[4 * 32 * 64];   // [chunk][b][jl] = 32 KB

    int tid = threadIdx.x;
    int jl  = tid & 63;
    int c   = tid >> 6;
    int jb  = blockIdx.x * 64 + jl;

    int n0 = __builtin_amdgcn_readfirstlane(c * 64);
    const float* selp = sel_w + n0;

    float wv[64];
#pragma unroll
    for (int n = 0; n < 64; ++n)
        wv[n] = w_bank[(size_t)(n0 + n) * WELEM + jb];

    float acc[BS];
#pragma unroll
    for (int b = 0; b < BS; ++b) acc[b] = 0.f;
#pragma unroll
    for (int b = 0; b < BS; ++b)
#pragma unroll
        for (int n = 0; n < 64; ++n)
            acc[b] = fmaf(selp[b * BANK + n], wv[n], acc[b]);

#pragma unroll
    for (int b = 0; b < BS; ++b)
        s_red[(c * 32 + b) * 64 + jl] = acc[b];
    __syncthreads();

    int B0  = (tid * 8) & 31;
    int jl2 = (tid * 8) >> 5;
    int j   = blockIdx.x * 64 + jl2;
    int o   = j / 576;
    int rem = j - o * 576;
    int i   = rem / 9;
    int tap = rem - i * 9;
    size_t base = ((size_t)tap * 8 + (i >> 3)) * 512 + (size_t)o * 8 + (i & 7);
#pragma unroll
    for (int u = 0; u < 8; ++u) {
        int b = B0 + u;
        float v = s_red[(0 * 32 + b) * 64 + jl2] + s_red[(1 * 32 + b) * 64 + jl2]
                + s_red[(2 * 32 + b) * 64 + jl2] + s_red[(3 * 32 + b) * 64 + jl2];
        short sv = f2bf(v);
        wmb[(size_t)b * (9 * 8 * 64 * 8) + base] = *reinterpret_cast<__hip_bfloat16*>(&sv);
    }
}

// ---------------- kernel 4: FUSED implicit-GEMM conv (reads fp32 NCHW) ------
// 2048 blocks = (b, 64 strips of 2 rows), XCD-swizzled; 512 thr / 8 waves.
// wave = (row wr, oc-half oh, px-half ph): 32 oc x 64 px -> 2 acc tiles.
// K: TWO chunks of 32 ic (halves sync events vs 4x16). LDS x-layout per buf:
// [ky4][P16][136 dwords], P = icpair; dword = bf16(ic=2P | 2P+1).
// Per chunk: {aA,aB areg loads; MFMA ks0; LOADX(next); MFMA ks1; STOREX; bar}.
__global__ __launch_bounds__(512, 4) void k_conv(const float* __restrict__ x,
                                                 const short* __restrict__ wmb,
                                                 const float* __restrict__ bias,
                                                 float* __restrict__ out) {
    __shared__ int   s_x[2][4 * 16 * 136];   // 8704 dwords = 34816 B per buf
    __shared__ float s_bias[OC];

    int orig    = blockIdx.x;
    int logical = (orig & 7) * 256 + (orig >> 3);   // bijective (2048%8==0)
    int b    = logical >> 6;
    int y0   = (logical & 63) * 2;
    int tid  = threadIdx.x;
    int lane = tid & 63;
    int wv   = tid >> 6;
    int h    = lane >> 5;
    int ln   = lane & 31;
    int wr   = wv & 1;
    int oh   = (wv >> 1) & 1;
    int ph   = wv >> 2;

    if (tid < OC) s_bias[tid] = bias[b * OC + tid];
    // zero halo slots (gx=-1 -> slot 3, gx=128 -> slot 132) for 64 rows x 2 bufs
    if (tid < 256) {
        int buf  = tid >> 7;
        int row  = (tid >> 1) & 63;
        int slot = (tid & 1) ? 132 : 3;
        s_x[buf][row * 136 + slot] = 0;
    }

    const float* xb   = x + (size_t)b * IC * PLANE;
    const short* wmbs = wmb + (size_t)b * 36864;

    // ---- staging descriptors: 2048 units/chunk, 4 per thread ----
    // u = k*512+tid -> ky=u>>9, P=(u>>5)&15, q=u&31
    int x_goff[4], x_lds[4], x_P[4]; bool x_ok[4];
#pragma unroll
    for (int k = 0; k < 4; ++k) {
        int u  = k * 512 + tid;
        int ky = u >> 9;
        int P  = (u >> 5) & 15;
        int q  = u & 31;
        int gy = y0 - 1 + ky;
        x_ok[k]   = ((unsigned)gy < (unsigned)HH);
        x_P[k]    = P;
        x_goff[k] = gy * WW + 4 * q;
        x_lds[k]  = (ky * 16 + P) * 136 + 4 + 4 * q;
    }

    float4 xlo[4], xhi[4];

    auto LOADX = [&](int cc) {
#pragma unroll
        for (int k = 0; k < 4; ++k) {
            if (x_ok[k]) {
                const float* p = xb + (size_t)(cc * 32 + 2 * x_P[k]) * PLANE + x_goff[k];
                xlo[k] = *(const float4*)p;
                xhi[k] = *(const float4*)(p + PLANE);
            } else {
                xlo[k] = make_float4(0.f, 0.f, 0.f, 0.f);
                xhi[k] = make_float4(0.f, 0.f, 0.f, 0.f);
            }
        }
    };
    auto STOREX = [&](int bf) {
#pragma unroll
        for (int k = 0; k < 4; ++k) {
            i32x4 d;
#pragma unroll
            for (int j = 0; j < 4; ++j)
                d[j] = cvt_pk_bf2(((const float*)&xlo[k])[j], ((const float*)&xhi[k])[j]);
            *(i32x4*)&s_x[bf][x_lds[k]] = d;      // b128, aligned, lane-contiguous
        }
    };

    f32x16 acc[2];
    acc[0] = (f32x16)0.0f;
    acc[1] = (f32x16)0.0f;

    LOADX(0);
    STOREX(0);
    __syncthreads();

#pragma unroll
    for (int cc = 0; cc < 2; ++cc) {
        // A-fragments for both K16-steps of this 32-ic chunk
        short8 aA[9], aB[9];
#pragma unroll
        for (int tap = 0; tap < 9; ++tap)
            aA[tap] = *(const short8*)(wmbs +
                (size_t)((tap * 8 + cc * 4 + h) * 64 + oh * 32 + ln) * 8);
#pragma unroll
        for (int tap = 0; tap < 9; ++tap)
            aB[tap] = *(const short8*)(wmbs +
                (size_t)((tap * 8 + cc * 4 + 2 + h) * 64 + oh * 32 + ln) * 8);

        const int* xi = (const int*)s_x[cc];

        // ---- ks = 0 ----
#pragma unroll
        for (int ky = 0; ky < 3; ++ky) {
#pragma unroll
            for (int kx = 0; kx < 3; ++kx) {
                short8 a = aA[ky * 3 + kx];
#pragma unroll
                for (int nt = 0; nt < 2; ++nt) {
                    int px   = ph * 64 + nt * 32 + ln;
                    int base = ((wr + ky) * 16 + h * 4) * 136 + px + kx + 3;
                    i32x4 d;
                    d[0] = xi[base];
                    d[1] = xi[base + 136];
                    d[2] = xi[base + 272];
                    d[3] = xi[base + 408];
                    short8 bb = __builtin_bit_cast(short8, d);
                    acc[nt] = __builtin_amdgcn_mfma_f32_32x32x16_bf16(a, bb, acc[nt], 0, 0, 0);
                }
            }
        }
        if (cc == 0) LOADX(1);          // in flight during ks1 MFMAs
        // ---- ks = 1 ----
#pragma unroll
        for (int ky = 0; ky < 3; ++ky) {
#pragma unroll
            for (int kx = 0; kx < 3; ++kx) {
                short8 a = aB[ky * 3 + kx];
#pragma unroll
                for (int nt = 0; nt < 2; ++nt) {
                    int px   = ph * 64 + nt * 32 + ln;
                    int base = ((wr + ky) * 16 + 8 + h * 4) * 136 + px + kx + 3;
                    i32x4 d;
                    d[0] = xi[base];
                    d[1] = xi[base + 136];
                    d[2] = xi[base + 272];
                    d[3] = xi[base + 408];
                    short8 bb = __builtin_bit_cast(short8, d);
                    acc[nt] = __builtin_amdgcn_mfma_f32_32x32x16_bf16(a, bb, acc[nt], 0, 0, 0);
                }
            }
        }
        if (cc == 0) {
            STOREX(1);                  // waits LOADX(1); lands after MFMAs
            __syncthreads();
        }
    }

    // epilogue: C/D layout col=lane&31, row=(r&3)+8*(r>>2)+4*h
    int y = y0 + wr;
    float* ob = out + (size_t)b * OC * PLANE;
#pragma unroll
    for (int nt = 0; nt < 2; ++nt) {
#pragma unroll
        for (int r = 0; r < 16; ++r) {
            int oc = oh * 32 + (r & 3) + 8 * (r >> 2) + 4 * h;
            int px = ph * 64 + nt * 32 + ln;
            ob[((size_t)oc * HH + y) * WW + px] = acc[nt][r] + s_bias[oc];
        }
    }
}

// ---------------------------------------------------------------------------
extern "C" void kernel_launch(void* const* d_in, const int* in_sizes, int n_in,
                              void* d_out, int out_size, void* d_ws, size_t ws_size,
                              hipStream_t stream) {
    const float* x      = (const float*)d_in[0];
    const float* w_addr = (const float*)d_in[1];
    const float* b_addr = (const float*)d_in[2];
    const float* w_bank = (const float*)d_in[3];
    const float* b_bank = (const float*)d_in[4];
    const float* aspace = (const float*)d_in[5];
    float* out = (float*)d_out;

    char* ws = (char*)d_ws;
    float*          sel_w = (float*)ws;                     // 32768 B
    float*          bias  = (float*)(ws + 32768);           //  8192 B
    __hip_bfloat16* wmb   = (__hip_bfloat16*)(ws + 40960);  // 2359296 B

    k_selw<<<BS, BANK, 0, stream>>>(w_addr, aspace, sel_w);
    k_bias<<<BS * 8, 256, 0, stream>>>(b_addr, aspace, b_bank, bias);
    k_wmix<<<WELEM / 64, 256, 0, stream>>>(sel_w, w_bank, wmb);
    k_conv<<<BS * 64, 512, 0, stream>>>(x, (const short*)wmb, bias, out);
}

// Round 16
// 129.584 us; speedup vs baseline: 1.0988x; 1.0988x over previous
//
#include <hip/hip_runtime.h>
#include <hip/hip_bf16.h>
#include <math.h>

#define BS   32
#define IC   64
#define OC   64
#define HH   128
#define WW   128
#define BANK 256
#define ADDR 64
#define WELEM (OC*IC*9)
#define PLANE (HH*WW)

typedef short short8 __attribute__((ext_vector_type(8)));
typedef float f32x16 __attribute__((ext_vector_type(16)));

__device__ __forceinline__ short f2bf(float f) {
    unsigned u = __builtin_bit_cast(unsigned, f);
    unsigned r = (u + 0x7FFFu + ((u >> 16) & 1u)) >> 16;
    return (short)r;
}

typedef __attribute__((address_space(3))) unsigned int lds_u32;
typedef const __attribute__((address_space(1))) unsigned int g_u32;
__device__ __forceinline__ void gload16(const short* g, short* l) {
    __builtin_amdgcn_global_load_lds((g_u32*)g, (lds_u32*)l, 16, 0, 0);
}

// ---------------- kernel 1: sel_w = softmax(w_addr @ aspace^T) --------------
__global__ __launch_bounds__(BANK) void k_selw(const float* __restrict__ w_addr,
                                               const float* __restrict__ aspace,
                                               float* __restrict__ sel_w) {
    int b = blockIdx.x;
    int n = threadIdx.x;
    const float* wa = w_addr + b * ADDR;
    const float* as = aspace + n * ADDR;
    float dot = 0.f;
#pragma unroll
    for (int k = 0; k < ADDR; ++k) dot = fmaf(wa[k], as[k], dot);

    __shared__ float red[BANK];
    red[n] = dot; __syncthreads();
    for (int s = BANK / 2; s > 0; s >>= 1) {
        if (n < s) red[n] = fmaxf(red[n], red[n + s]);
        __syncthreads();
    }
    float m = red[0]; __syncthreads();
    float e = expf(dot - m);
    red[n] = e; __syncthreads();
    for (int s = BANK / 2; s > 0; s >>= 1) {
        if (n < s) red[n] += red[n + s];
        __syncthreads();
    }
    sel_w[b * BANK + n] = e / red[0];
}

// ---------------- kernel 2: bias[b][o] (R12-proven) -------------------------
__global__ __launch_bounds__(256) void k_bias(const float* __restrict__ b_addr,
                                              const float* __restrict__ aspace,
                                              const float* __restrict__ b_bank,
                                              float* __restrict__ bias) {
    __shared__ float s_m[256], s_s[256], s_w[256];
    int blk = blockIdx.x;            // b*8 + og
    int b   = blk >> 3;
    int og  = blk & 7;
    int tid = threadIdx.x;
    int ol  = tid >> 5;              // 0..7
    int o   = og * 8 + ol;
    int q   = tid & 31;              // n-slice: n = q*8 .. q*8+7

    const float* ba = b_addr + ((size_t)b * OC + o) * ADDR;
    float bav[64];
#pragma unroll
    for (int i = 0; i < 16; ++i)
        *(float4*)&bav[i * 4] = *(const float4*)&ba[i * 4];

    float d[8];
#pragma unroll
    for (int n = 0; n < 8; ++n) {
        const float* ar = aspace + (size_t)(q * 8 + n) * ADDR;
        float s = 0.f;
#pragma unroll
        for (int k = 0; k < 64; ++k) s = fmaf(bav[k], ar[k], s);
        d[n] = s;
    }
    float mx = d[0];
#pragma unroll
    for (int n = 1; n < 8; ++n) mx = fmaxf(mx, d[n]);
    s_m[ol * 32 + q] = mx;
    __syncthreads();
    float M = -1e30f;
    for (int j = 0; j < 32; ++j) M = fmaxf(M, s_m[ol * 32 + j]);

    float s = 0.f, ws = 0.f;
#pragma unroll
    for (int n = 0; n < 8; ++n) {
        float e = expf(d[n] - M);
        s += e;
        ws += e * b_bank[q * 8 + n];
    }
    s_s[ol * 32 + q] = s;
    s_w[ol * 32 + q] = ws;
    __syncthreads();
    if (q == 0) {
        float S = 0.f, W = 0.f;
        for (int j = 0; j < 32; ++j) { S += s_s[ol * 32 + j]; W += s_w[ol * 32 + j]; }
        bias[b * OC + o] = W / S;
    }
}

// ---------------- kernel 3: weight mix -> bf16 (R5-proven split-K) ----------
// wmb[b][tap(9)][icg(8)][oc(64)][ic8(8)]  (bf16)
__global__ __launch_bounds__(256) void k_wmix(const float* __restrict__ sel_w,
                                              const float* __restrict__ w_bank,
                                              __hip_bfloat16* __restrict__ wmb) {
    __shared__ float s_red[4 * 32 * 64];   // [chunk][b][jl] = 32 KB

    int tid = threadIdx.x;
    int jl  = tid & 63;
    int c   = tid >> 6;
    int jb  = blockIdx.x * 64 + jl;

    int n0 = __builtin_amdgcn_readfirstlane(c * 64);
    const float* selp = sel_w + n0;

    float wv[64];
#pragma unroll
    for (int n = 0; n < 64; ++n)
        wv[n] = w_bank[(size_t)(n0 + n) * WELEM + jb];

    float acc[BS];
#pragma unroll
    for (int b = 0; b < BS; ++b) acc[b] = 0.f;
#pragma unroll
    for (int b = 0; b < BS; ++b)
#pragma unroll
        for (int n = 0; n < 64; ++n)
            acc[b] = fmaf(selp[b * BANK + n], wv[n], acc[b]);

#pragma unroll
    for (int b = 0; b < BS; ++b)
        s_red[(c * 32 + b) * 64 + jl] = acc[b];
    __syncthreads();

    int B0  = (tid * 8) & 31;
    int jl2 = (tid * 8) >> 5;
    int j   = blockIdx.x * 64 + jl2;
    int o   = j / 576;
    int rem = j - o * 576;
    int i   = rem / 9;
    int tap = rem - i * 9;
    size_t base = ((size_t)tap * 8 + (i >> 3)) * 512 + (size_t)o * 8 + (i & 7);
#pragma unroll
    for (int u = 0; u < 8; ++u) {
        int b = B0 + u;
        float v = s_red[(0 * 32 + b) * 64 + jl2] + s_red[(1 * 32 + b) * 64 + jl2]
                + s_red[(2 * 32 + b) * 64 + jl2] + s_red[(3 * 32 + b) * 64 + jl2];
        short sv = f2bf(v);
        wmb[(size_t)b * (9 * 8 * 64 * 8) + base] = *reinterpret_cast<__hip_bfloat16*>(&sv);
    }
}

// ---------------- kernel 4: FUSED implicit-GEMM conv (R9-proven, 86us) ------
// 2048 blocks = (b, 64 strips of 2 rows), XCD-swizzled; 512 thr / 8 waves.
// wave = (row wr, oc-half oh, px-half ph): 32 oc x 64 px -> 2 acc tiles.
// K: 4 chunks of 16 ic. Double-buffered LDS, one barrier per chunk.
// x staging: reg (8 plane-strided scalars -> 1 ds_write_b128, conflict-free).
// w staging: global_load_lds (contiguous 1KB slices, zero reg pressure).
__global__ __launch_bounds__(512, 2) void k_conv(const float* __restrict__ x,
                                                 const short* __restrict__ wmb,
                                                 const float* __restrict__ bias,
                                                 float* __restrict__ out) {
    __shared__ short s_x[2][4 * 2 * 132 * 8];  // [buf][ky][g][col(132)][ic8]
    __shared__ short s_w[2][9 * 2 * 64 * 8];   // [buf][tap][g][oc][ic8]
    __shared__ float s_bias[OC];

    int orig    = blockIdx.x;
    int logical = (orig & 7) * 256 + (orig >> 3);   // bijective (2048%8==0)
    int b    = logical >> 6;
    int y0   = (logical & 63) * 2;
    int tid  = threadIdx.x;
    int lane = tid & 63;
    int wv   = tid >> 6;
    int h    = lane >> 5;
    int ln   = lane & 31;
    int wr   = wv & 1;
    int oh   = (wv >> 1) & 1;
    int ph   = wv >> 2;

    if (tid < OC) s_bias[tid] = bias[b * OC + tid];
    // halo cols 0 and 129 are structurally zero: zero once, never rewritten
    if (tid < 32) {
        int bf   = tid >> 4;
        int kg   = (tid >> 1) & 7;       // ky*2+g
        int col  = (tid & 1) ? 129 : 0;
        *(short8*)&s_x[bf][(kg * 132 + col) * 8] = (short8){0,0,0,0,0,0,0,0};
    }

    const float* xb   = x + (size_t)b * IC * PLANE;
    const short* wmbs = wmb + (size_t)b * 36864;

    // ---- x staging descriptors: unit u = k*512+tid, u<1024 ----
    // u -> (ky=u>>8, g=(u>>7)&1, cx=u&127); col=cx+1; 8 ic loads per unit.
    int x_goff[2], x_lds[2]; bool x_ok[2]; int x_g[2];
#pragma unroll
    for (int k = 0; k < 2; ++k) {
        int u  = k * 512 + tid;
        int ky = u >> 8;
        int g  = (u >> 7) & 1;
        int cx = u & 127;
        int gy = y0 - 1 + ky;
        x_ok[k]   = ((unsigned)gy < (unsigned)HH);
        x_g[k]    = g;
        x_goff[k] = gy * WW + cx;
        x_lds[k]  = ((ky * 2 + g) * 132 + cx + 1) * 8;
    }

    float xr[2][8];

    auto LOADX = [&](int cc) {
#pragma unroll
        for (int k = 0; k < 2; ++k) {
            if (x_ok[k]) {
                const float* p = xb + (size_t)(cc * 16 + x_g[k] * 8) * PLANE + x_goff[k];
#pragma unroll
                for (int e = 0; e < 8; ++e) xr[k][e] = p[(size_t)e * PLANE];
            } else {
#pragma unroll
                for (int e = 0; e < 8; ++e) xr[k][e] = 0.f;
            }
        }
    };
    // w: 18 slices (tap,g); each slice 64 lanes x 16B contiguous, linear dest
    auto STAGEW = [&](int cc, int bf) {
        for (int s = wv; s < 18; s += 8) {
            int tap = s >> 1, g = s & 1;
            const short* gsrc = wmbs + (size_t)((tap * 8 + 2 * cc + g) * 64 + lane) * 8;
            gload16(gsrc, &s_w[bf][((tap * 2 + g) * 64) * 8]);
        }
    };
    auto STOREX = [&](int bf) {
#pragma unroll
        for (int k = 0; k < 2; ++k) {
            short8 s;
#pragma unroll
            for (int e = 0; e < 8; ++e) s[e] = f2bf(xr[k][e]);
            *(short8*)&s_x[bf][x_lds[k]] = s;           // b128, lane-contiguous
        }
    };

    f32x16 acc[2];
    acc[0] = (f32x16)0.0f;
    acc[1] = (f32x16)0.0f;

    LOADX(0);
    STAGEW(0, 0);
    STOREX(0);
    __syncthreads();

#pragma unroll
    for (int cc = 0; cc < 4; ++cc) {
        int bf = cc & 1;
        if (cc < 3) {
            LOADX(cc + 1);                 // x -> regs, in flight during MFMA
            STAGEW(cc + 1, bf ^ 1);        // w -> LDS direct, in flight
            __builtin_amdgcn_sched_barrier(0);   // forbid sinking loads below
        }
        const short8* xb8 = (const short8*)s_x[bf];
        const short8* wb8 = (const short8*)s_w[bf];
#pragma unroll
        for (int ky = 0; ky < 3; ++ky) {
#pragma unroll
            for (int kx = 0; kx < 3; ++kx) {
                short8 a = wb8[((ky * 3 + kx) * 2 + h) * 64 + oh * 32 + ln];
#pragma unroll
                for (int nt = 0; nt < 2; ++nt) {
                    short8 bb = xb8[((wr + ky) * 2 + h) * 132 + ph * 64 + nt * 32 + ln + kx];
                    acc[nt] = __builtin_amdgcn_mfma_f32_32x32x16_bf16(a, bb, acc[nt], 0, 0, 0);
                }
            }
        }
        if (cc < 3) STOREX(bf ^ 1);        // waits xr; vmcnt drain after MFMA
        __syncthreads();
    }

    // epilogue: C/D layout col=lane&31, row=(r&3)+8*(r>>2)+4*h
    int y = y0 + wr;
    float* ob = out + (size_t)b * OC * PLANE;
#pragma unroll
    for (int nt = 0; nt < 2; ++nt) {
#pragma unroll
        for (int r = 0; r < 16; ++r) {
            int oc = oh * 32 + (r & 3) + 8 * (r >> 2) + 4 * h;
            int px = ph * 64 + nt * 32 + ln;
            ob[((size_t)oc * HH + y) * WW + px] = acc[nt][r] + s_bias[oc];
        }
    }
}

// ---------------------------------------------------------------------------
extern "C" void kernel_launch(void* const* d_in, const int* in_sizes, int n_in,
                              void* d_out, int out_size, void* d_ws, size_t ws_size,
                              hipStream_t stream) {
    const float* x      = (const float*)d_in[0];
    const float* w_addr = (const float*)d_in[1];
    const float* b_addr = (const float*)d_in[2];
    const float* w_bank = (const float*)d_in[3];
    const float* b_bank = (const float*)d_in[4];
    const float* aspace = (const float*)d_in[5];
    float* out = (float*)d_out;

    char* ws = (char*)d_ws;
    float*          sel_w = (float*)ws;                     // 32768 B
    float*          bias  = (float*)(ws + 32768);           //  8192 B
    __hip_bfloat16* wmb   = (__hip_bfloat16*)(ws + 40960);  // 2359296 B

    k_selw<<<BS, BANK, 0, stream>>>(w_addr, aspace, sel_w);
    k_bias<<<BS * 8, 256, 0, stream>>>(b_addr, aspace, b_bank, bias);
    k_wmix<<<WELEM / 64, 256, 0, stream>>>(sel_w, w_bank, wmb);
    k_conv<<<BS * 64, 512, 0, stream>>>(x, (const short*)wmb, bias, out);
}